// Round 1
// baseline (5424.835 us; speedup 1.0000x reference)
//
#include <hip/hip_runtime.h>
#include <cstdint>
#include <cstddef>

// ---------------------------------------------------------------------------
// TLSTM: B=64, S=512, I=256, H=256
//   Xg = inputs @ Wg^T + Wg_b + b_g + Ug_b   (g = i,f,o,c)   [bf16 MFMA GEMM]
//   per step: C_ST = tanh(c @ Wd^T + Wd_b + bd)
//             c    = c + (T-1)*C_ST,  T = 1/log(ts + 2.7183)
//             i,f,o = sigm(Xg + h @ Ug^T),  Cn = tanh(Xc + h @ Uc^T)
//             c = f*c + i*Cn ; h = o*tanh(c)
// d_out = [outputs, outputs, cell_states]  (fp32)
// ---------------------------------------------------------------------------

#define B_   64
#define S_   512
#define H_   256
#define BS_  (B_ * S_)            // 32768
#define BSH_ ((size_t)B_ * S_ * H_)  // 8388608

typedef _Float16 f16;
typedef _Float16 f16x2 __attribute__((ext_vector_type(2)));
typedef _Float16 f16x4 __attribute__((ext_vector_type(4)));
typedef short    s16x8 __attribute__((ext_vector_type(8)));
typedef float    f32x4 __attribute__((ext_vector_type(4)));

static __device__ __forceinline__ unsigned short f32_to_bf16(float f) {
    union { float f; uint32_t u; } v; v.f = f;
    uint32_t u = v.u;
    u += 0x7fffu + ((u >> 16) & 1u);   // RTNE
    return (unsigned short)(u >> 16);
}

static __device__ __forceinline__ float fdot2f(f16x2 a, f16x2 b, float c) {
#if __has_builtin(__builtin_amdgcn_fdot2)
    return __builtin_amdgcn_fdot2(a, b, c, false);
#else
    return c + (float)a[0] * (float)b[0] + (float)a[1] * (float)b[1];
#endif
}

static __device__ __forceinline__ float sigm(float z) {
    return 1.0f / (1.0f + __expf(-z));
}
static __device__ __forceinline__ float tanh_fast(float z) {
    float e = __expf(-2.0f * fabsf(z));
    float t = (1.0f - e) / (1.0f + e);
    return z >= 0.0f ? t : -t;
}

// ---------------------------------------------------------------------------
// prep: W4 (bf16, [1024][256], rows = gate outputs i,f,o,c) + fused bias4
// ---------------------------------------------------------------------------
__global__ void prep_w4(const float* __restrict__ Wi, const float* __restrict__ Wf,
                        const float* __restrict__ Wo, const float* __restrict__ Wc,
                        const float* __restrict__ Wib, const float* __restrict__ Wfb,
                        const float* __restrict__ Wob, const float* __restrict__ Wcb,
                        const float* __restrict__ Uib, const float* __restrict__ Ufb,
                        const float* __restrict__ Uob, const float* __restrict__ Ucb,
                        const float* __restrict__ bi,  const float* __restrict__ bf_,
                        const float* __restrict__ bo,  const float* __restrict__ bc,
                        unsigned short* __restrict__ W4, float* __restrict__ bias4) {
    const int n = blockIdx.x;        // 0..1023
    const int k = threadIdx.x;       // 0..255
    const int g = n >> 8, o = n & 255;
    const float* W = (g == 0) ? Wi : (g == 1) ? Wf : (g == 2) ? Wo : Wc;
    W4[n * 256 + k] = f32_to_bf16(W[o * 256 + k]);
    if (k == 0) {
        const float* wb = (g == 0) ? Wib : (g == 1) ? Wfb : (g == 2) ? Wob : Wcb;
        const float* ub = (g == 0) ? Uib : (g == 1) ? Ufb : (g == 2) ? Uob : Ucb;
        const float* sb = (g == 0) ? bi  : (g == 1) ? bf_ : (g == 2) ? bo  : bc;
        bias4[n] = wb[o] + ub[o] + sb[o];   // fold U-bias into the x-projection
    }
}

// ---------------------------------------------------------------------------
// prep: UTP f16-pair layout  UTP[kk][n] = (U_n[2kk], U_n[2kk+1]),
// n = gate*256+o over [Ui,Uf,Uo,Uc,Wd]  -> [128][1280] f16x2
// ---------------------------------------------------------------------------
__global__ void prep_utp(const float* __restrict__ Ui, const float* __restrict__ Uf,
                         const float* __restrict__ Uo, const float* __restrict__ Uc,
                         const float* __restrict__ Wd, f16x2* __restrict__ UTP) {
    const int n  = blockIdx.x;       // 0..1279
    const int kk = threadIdx.x;      // 0..127
    const int g = n >> 8, o = n & 255;
    const float* U = (g == 0) ? Ui : (g == 1) ? Uf : (g == 2) ? Uo : (g == 3) ? Uc : Wd;
    float2 v = *reinterpret_cast<const float2*>(U + o * 256 + 2 * kk);
    f16x2 p; p[0] = (f16)v.x; p[1] = (f16)v.y;
    UTP[(size_t)kk * 1280 + n] = p;
}

// ---------------------------------------------------------------------------
// Projection GEMM: Xbuf[m][n] = inputs[m][:] . W4[n][:] + bias4[n]   (f16 out)
// m = b*512+s (32768), n = gate*256+j (1024). bf16 MFMA 16x16x32, 64x64 tiles.
// ---------------------------------------------------------------------------
__global__ __launch_bounds__(256) void proj_gemm(const float* __restrict__ X,
        const unsigned short* __restrict__ W4, const float* __restrict__ bias4,
        f16* __restrict__ Xbuf) {
    __shared__ __align__(16) unsigned short a_s[64 * 40];  // [row][32+8pad]
    __shared__ __align__(16) unsigned short b_s[64 * 40];
    const int bid = blockIdx.x;
    const int m0 = (bid >> 4) * 64;
    const int n0 = (bid & 15) * 64;
    const int tid  = threadIdx.x;
    const int lane = tid & 63;
    const int w    = tid >> 6;          // wave 0..3 -> M rows w*16..w*16+15
    const int srow = tid >> 2;          // staging: 0..63
    const int scol = (tid & 3) * 8;     // staging: 0,8,16,24
    const int r  = lane & 15;
    const int kg = lane >> 4;

    f32x4 acc[4] = {{0,0,0,0},{0,0,0,0},{0,0,0,0},{0,0,0,0}};

    for (int kt = 0; kt < 8; ++kt) {
        const int k0 = kt * 32;
        // stage A (fp32 -> bf16)
        float4 av0 = *reinterpret_cast<const float4*>(X + (size_t)(m0 + srow) * 256 + k0 + scol);
        float4 av1 = *reinterpret_cast<const float4*>(X + (size_t)(m0 + srow) * 256 + k0 + scol + 4);
        union { unsigned short us[8]; uint4 v; } pk;
        pk.us[0] = f32_to_bf16(av0.x); pk.us[1] = f32_to_bf16(av0.y);
        pk.us[2] = f32_to_bf16(av0.z); pk.us[3] = f32_to_bf16(av0.w);
        pk.us[4] = f32_to_bf16(av1.x); pk.us[5] = f32_to_bf16(av1.y);
        pk.us[6] = f32_to_bf16(av1.z); pk.us[7] = f32_to_bf16(av1.w);
        *reinterpret_cast<uint4*>(a_s + srow * 40 + scol) = pk.v;
        // stage B (already bf16)
        uint4 bv = *reinterpret_cast<const uint4*>(W4 + (size_t)(n0 + srow) * 256 + k0 + scol);
        *reinterpret_cast<uint4*>(b_s + srow * 40 + scol) = bv;
        __syncthreads();

        // A-frag: lane holds A[m = r][k = kg*8 + j]
        s16x8 af = *reinterpret_cast<const s16x8*>(a_s + (w * 16 + r) * 40 + kg * 8);
        #pragma unroll
        for (int nt = 0; nt < 4; ++nt) {
            // B-frag: lane holds B[k = kg*8 + j][n = r]  (= W4[n][k], contiguous)
            s16x8 bfr = *reinterpret_cast<const s16x8*>(b_s + (nt * 16 + r) * 40 + kg * 8);
            acc[nt] = __builtin_amdgcn_mfma_f32_16x16x32_bf16(af, bfr, acc[nt], 0, 0, 0);
        }
        __syncthreads();
    }
    // D: col = lane&15, row = (lane>>4)*4 + reg   [m89-verified]
    #pragma unroll
    for (int nt = 0; nt < 4; ++nt) {
        const int n = n0 + nt * 16 + r;
        const float bn = bias4[n];
        #pragma unroll
        for (int reg = 0; reg < 4; ++reg) {
            const int m = m0 + w * 16 + kg * 4 + reg;
            Xbuf[(size_t)m * 1024 + n] = (f16)(acc[nt][reg] + bn);
        }
    }
}

// ---------------------------------------------------------------------------
// Recurrence: 32 blocks x 640 threads, 2 batches/block.
// Phase A: 640 threads x 2 outputs x 2 batches -> 1280 preacts via v_dot2 f16.
// Phase B: 512 threads: gates + state update + 3 output stores.
// Phase C: pack h/c into interleaved f16x4 pairs for next step.
// ---------------------------------------------------------------------------
__global__ __launch_bounds__(640) void recur(const float* __restrict__ tsp,
        const f16x2* __restrict__ UTP, const f16* __restrict__ Xbuf,
        const float* __restrict__ Wdb, const float* __restrict__ bdv,
        float* __restrict__ out) {
    __shared__ float h0[256], h1[256], c0[256], c1[256];
    __shared__ f16x4 hpi[128];   // {h0[2k],h0[2k+1],h1[2k],h1[2k+1]}
    __shared__ f16x4 cpi[128];
    __shared__ float pre0[1280], pre1[1280];
    __shared__ float bDs[256];

    const int tid = threadIdx.x;
    const int b0 = blockIdx.x * 2;

    if (tid < 256) {
        h0[tid] = 0.f; h1[tid] = 0.f; c0[tid] = 0.f; c1[tid] = 0.f;
        bDs[tid] = Wdb[tid] + bdv[tid];
    }
    if (tid < 128) {
        f16x4 z; z[0] = (f16)0; z[1] = (f16)0; z[2] = (f16)0; z[3] = (f16)0;
        hpi[tid] = z; cpi[tid] = z;
    }
    __syncthreads();

    const int n0 = tid * 2;                       // output pair this thread owns
    const bool isWd = (n0 >= 1024);               // waves 8,9 -> Wd (input = c)
    const f16x4* vp   = isWd ? cpi : hpi;
    const f16x2* wrow = UTP + n0;
    const int bl = tid >> 8;                      // 0/1 for tid<512
    const int j  = tid & 255;

    for (int s = 0; s < 512; ++s) {
        // prefetch x-projections + timestamp (consumed in phase B, hidden by dots)
        float xi = 0.f, xfv = 0.f, xov = 0.f, xcv = 0.f, ts = 0.f;
        size_t mB = 0;
        if (tid < 512) {
            const int bb = b0 + bl;
            mB = (size_t)bb * 512 + s;
            const f16* xp = Xbuf + mB * 1024 + j;
            xi  = (float)xp[0];   xfv = (float)xp[256];
            xov = (float)xp[512]; xcv = (float)xp[768];
            ts = tsp[bb * 512 + s];
        }

        float a00 = 0.f, a01 = 0.f, a10 = 0.f, a11 = 0.f;
        #pragma unroll 16
        for (int kk = 0; kk < 128; ++kk) {
            f16x4 wv = *reinterpret_cast<const f16x4*>(wrow + (size_t)kk * 1280);
            f16x4 v  = vp[kk];
            f16x2 wa = __builtin_shufflevector(wv, wv, 0, 1);
            f16x2 wb = __builtin_shufflevector(wv, wv, 2, 3);
            f16x2 v0 = __builtin_shufflevector(v, v, 0, 1);
            f16x2 v1 = __builtin_shufflevector(v, v, 2, 3);
            a00 = fdot2f(wa, v0, a00);
            a01 = fdot2f(wb, v0, a01);
            a10 = fdot2f(wa, v1, a10);
            a11 = fdot2f(wb, v1, a11);
        }
        pre0[n0] = a00; pre0[n0 + 1] = a01;
        pre1[n0] = a10; pre1[n0 + 1] = a11;
        __syncthreads();

        if (tid < 512) {
            const float* pre = bl ? pre1 : pre0;
            float cold = (bl ? c1 : c0)[j];
            float t = 1.0f / __logf(ts + 2.7183f);
            float CST  = tanh_fast(pre[1024 + j] + bDs[j]);
            float cdec = cold + (t - 1.0f) * CST;
            float ig = sigm(xi  + pre[j]);
            float fg = sigm(xfv + pre[256 + j]);
            float og = sigm(xov + pre[512 + j]);
            float Cn = tanh_fast(xcv + pre[768 + j]);
            float cn = fg * cdec + ig * Cn;
            float hn = og * tanh_fast(cn);
            (bl ? c1 : c0)[j] = cn;
            (bl ? h1 : h0)[j] = hn;
            const size_t oi = mB * 256 + j;
            out[oi]            = hn;   // outputs
            out[BSH_ + oi]     = hn;   // outputs (duplicated in return tuple)
            out[2 * BSH_ + oi] = cn;   // cell_states
        }
        __syncthreads();

        if (tid < 128) {
            f16x4 hv;
            hv[0] = (f16)h0[2 * tid]; hv[1] = (f16)h0[2 * tid + 1];
            hv[2] = (f16)h1[2 * tid]; hv[3] = (f16)h1[2 * tid + 1];
            hpi[tid] = hv;
        } else if (tid < 256) {
            const int j2 = tid - 128;
            f16x4 cv;
            cv[0] = (f16)c0[2 * j2]; cv[1] = (f16)c0[2 * j2 + 1];
            cv[2] = (f16)c1[2 * j2]; cv[3] = (f16)c1[2 * j2 + 1];
            cpi[j2] = cv;
        }
        __syncthreads();
    }
}

// ---------------------------------------------------------------------------
extern "C" void kernel_launch(void* const* d_in, const int* in_sizes, int n_in,
                              void* d_out, int out_size, void* d_ws, size_t ws_size,
                              hipStream_t stream) {
    const float* inputs = (const float*)d_in[0];
    const float* tsp    = (const float*)d_in[1];
    const float* Wi_w = (const float*)d_in[2],  * Wi_b = (const float*)d_in[3];
    const float* Ui_w = (const float*)d_in[4],  * Ui_b = (const float*)d_in[5];
    const float* Wf_w = (const float*)d_in[6],  * Wf_b = (const float*)d_in[7];
    const float* Uf_w = (const float*)d_in[8],  * Uf_b = (const float*)d_in[9];
    const float* Wo_w = (const float*)d_in[10], * Wo_b = (const float*)d_in[11];
    const float* Uo_w = (const float*)d_in[12], * Uo_b = (const float*)d_in[13];
    const float* Wc_w = (const float*)d_in[14], * Wc_b = (const float*)d_in[15];
    const float* Uc_w = (const float*)d_in[16], * Uc_b = (const float*)d_in[17];
    const float* Wd_w = (const float*)d_in[18], * Wd_b = (const float*)d_in[19];
    const float* bi = (const float*)d_in[20], * bf_ = (const float*)d_in[21];
    const float* bo = (const float*)d_in[22], * bc  = (const float*)d_in[23];
    const float* bd = (const float*)d_in[24];

    // workspace layout (all 16B-aligned):
    //   Xbuf  f16  [32768][1024]  67,108,864 B
    //   W4    bf16 [1024][256]       524,288 B
    //   bias4 f32  [1024]               4,096 B
    //   UTP   f16x2[128][1280]        655,360 B   (total ~68.3 MB)
    char* ws = (char*)d_ws;
    f16*            Xbuf  = (f16*)ws;
    unsigned short* W4    = (unsigned short*)(ws + 67108864);
    float*          bias4 = (float*)(ws + 67633152);
    f16x2*          UTP   = (f16x2*)(ws + 67637248);

    prep_w4<<<1024, 256, 0, stream>>>(Wi_w, Wf_w, Wo_w, Wc_w,
                                      Wi_b, Wf_b, Wo_b, Wc_b,
                                      Ui_b, Uf_b, Uo_b, Uc_b,
                                      bi, bf_, bo, bc, W4, bias4);
    prep_utp<<<1280, 128, 0, stream>>>(Ui_w, Uf_w, Uo_w, Uc_w, Wd_w, UTP);
    proj_gemm<<<8192, 256, 0, stream>>>(inputs, W4, bias4, Xbuf);
    recur<<<32, 640, 0, stream>>>(tsp, UTP, Xbuf, Wd_b, bd, (float*)d_out);
}

// Round 2
// 3402.014 us; speedup vs baseline: 1.5946x; 1.5946x over previous
//
#include <hip/hip_runtime.h>
#include <cstdint>
#include <cstddef>

// ---------------------------------------------------------------------------
// TLSTM: B=64, S=512, I=256, H=256
// R2: register-resident weights. 4 blocks per batch, each owns 64 rows of all
// five matrices (Ui,Uf,Uo,Uc,Wd) in VGPRs (128 regs/thread). Per-step 4-block
// h/c exchange via agent-scope tags (parity double-buffered).
// ---------------------------------------------------------------------------

#define B_   64
#define S_   512
#define H_   256
#define BSH_ ((size_t)B_ * S_ * H_)  // 8388608

typedef _Float16 f16;
typedef _Float16 f16x2 __attribute__((ext_vector_type(2)));
typedef _Float16 f16x8 __attribute__((ext_vector_type(8)));
typedef short    s16x8 __attribute__((ext_vector_type(8)));
typedef float    f32x4 __attribute__((ext_vector_type(4)));

static __device__ __forceinline__ unsigned short f32_to_bf16(float f) {
    union { float f; uint32_t u; } v; v.f = f;
    uint32_t u = v.u;
    u += 0x7fffu + ((u >> 16) & 1u);   // RTNE
    return (unsigned short)(u >> 16);
}

static __device__ __forceinline__ float fdot2f(f16x2 a, f16x2 b, float c) {
#if __has_builtin(__builtin_amdgcn_fdot2)
    return __builtin_amdgcn_fdot2(a, b, c, false);
#else
    return c + (float)a[0] * (float)b[0] + (float)a[1] * (float)b[1];
#endif
}

static __device__ __forceinline__ float sigm(float z) {
    return 1.0f / (1.0f + __expf(-z));
}
static __device__ __forceinline__ float tanh_fast(float z) {
    float e = __expf(-2.0f * fabsf(z));
    float t = (1.0f - e) / (1.0f + e);
    return z >= 0.0f ? t : -t;
}

// ---------------------------------------------------------------------------
// prep: W4 (bf16, [1024][256]) + fused bias4 (Wg_b + b_g + Ug_b)
// ---------------------------------------------------------------------------
__global__ void prep_w4(const float* __restrict__ Wi, const float* __restrict__ Wf,
                        const float* __restrict__ Wo, const float* __restrict__ Wc,
                        const float* __restrict__ Wib, const float* __restrict__ Wfb,
                        const float* __restrict__ Wob, const float* __restrict__ Wcb,
                        const float* __restrict__ Uib, const float* __restrict__ Ufb,
                        const float* __restrict__ Uob, const float* __restrict__ Ucb,
                        const float* __restrict__ bi,  const float* __restrict__ bf_,
                        const float* __restrict__ bo,  const float* __restrict__ bc,
                        unsigned short* __restrict__ W4, float* __restrict__ bias4) {
    const int n = blockIdx.x;        // 0..1023
    const int k = threadIdx.x;       // 0..255
    const int g = n >> 8, o = n & 255;
    const float* W = (g == 0) ? Wi : (g == 1) ? Wf : (g == 2) ? Wo : Wc;
    W4[n * 256 + k] = f32_to_bf16(W[o * 256 + k]);
    if (k == 0) {
        const float* wb = (g == 0) ? Wib : (g == 1) ? Wfb : (g == 2) ? Wob : Wcb;
        const float* ub = (g == 0) ? Uib : (g == 1) ? Ufb : (g == 2) ? Uob : Ucb;
        const float* sb = (g == 0) ? bi  : (g == 1) ? bf_ : (g == 2) ? bo  : bc;
        bias4[n] = wb[o] + ub[o] + sb[o];
    }
}

// ---------------------------------------------------------------------------
// prep: Wpk f16 row-major [1280][256], rows n = g*256 + o, g in [Ui,Uf,Uo,Uc,Wd]
// ---------------------------------------------------------------------------
__global__ void prep_wrow(const float* __restrict__ Ui, const float* __restrict__ Uf,
                          const float* __restrict__ Uo, const float* __restrict__ Uc,
                          const float* __restrict__ Wd, f16* __restrict__ Wpk) {
    const int n = blockIdx.x;        // 0..1279
    const int k = threadIdx.x;       // 0..255
    const int g = n >> 8, o = n & 255;
    const float* U = (g == 0) ? Ui : (g == 1) ? Uf : (g == 2) ? Uo : (g == 3) ? Uc : Wd;
    Wpk[(size_t)n * 256 + k] = (f16)U[o * 256 + k];
}

// zero the sync tags (must run every launch; graph replays it)
__global__ void prep_zero(unsigned int* __restrict__ tags) {
    tags[blockIdx.x * 256 + threadIdx.x] = 0u;
}

// ---------------------------------------------------------------------------
// Projection GEMM (unchanged from R1): Xbuf[m][n] f16, bias folded.
// ---------------------------------------------------------------------------
__global__ __launch_bounds__(256) void proj_gemm(const float* __restrict__ X,
        const unsigned short* __restrict__ W4, const float* __restrict__ bias4,
        f16* __restrict__ Xbuf) {
    __shared__ __align__(16) unsigned short a_s[64 * 40];
    __shared__ __align__(16) unsigned short b_s[64 * 40];
    const int bid = blockIdx.x;
    const int m0 = (bid >> 4) * 64;
    const int n0 = (bid & 15) * 64;
    const int tid  = threadIdx.x;
    const int lane = tid & 63;
    const int w    = tid >> 6;
    const int srow = tid >> 2;
    const int scol = (tid & 3) * 8;
    const int r  = lane & 15;
    const int kg = lane >> 4;

    f32x4 acc[4] = {{0,0,0,0},{0,0,0,0},{0,0,0,0},{0,0,0,0}};

    for (int kt = 0; kt < 8; ++kt) {
        const int k0 = kt * 32;
        float4 av0 = *reinterpret_cast<const float4*>(X + (size_t)(m0 + srow) * 256 + k0 + scol);
        float4 av1 = *reinterpret_cast<const float4*>(X + (size_t)(m0 + srow) * 256 + k0 + scol + 4);
        union { unsigned short us[8]; uint4 v; } pk;
        pk.us[0] = f32_to_bf16(av0.x); pk.us[1] = f32_to_bf16(av0.y);
        pk.us[2] = f32_to_bf16(av0.z); pk.us[3] = f32_to_bf16(av0.w);
        pk.us[4] = f32_to_bf16(av1.x); pk.us[5] = f32_to_bf16(av1.y);
        pk.us[6] = f32_to_bf16(av1.z); pk.us[7] = f32_to_bf16(av1.w);
        *reinterpret_cast<uint4*>(a_s + srow * 40 + scol) = pk.v;
        uint4 bv = *reinterpret_cast<const uint4*>(W4 + (size_t)(n0 + srow) * 256 + k0 + scol);
        *reinterpret_cast<uint4*>(b_s + srow * 40 + scol) = bv;
        __syncthreads();

        s16x8 af = *reinterpret_cast<const s16x8*>(a_s + (w * 16 + r) * 40 + kg * 8);
        #pragma unroll
        for (int nt = 0; nt < 4; ++nt) {
            s16x8 bfr = *reinterpret_cast<const s16x8*>(b_s + (nt * 16 + r) * 40 + kg * 8);
            acc[nt] = __builtin_amdgcn_mfma_f32_16x16x32_bf16(af, bfr, acc[nt], 0, 0, 0);
        }
        __syncthreads();
    }
    #pragma unroll
    for (int nt = 0; nt < 4; ++nt) {
        const int n = n0 + nt * 16 + r;
        const float bn = bias4[n];
        #pragma unroll
        for (int reg = 0; reg < 4; ++reg) {
            const int m = m0 + w * 16 + kg * 4 + reg;
            Xbuf[(size_t)m * 1024 + n] = (f16)(acc[nt][reg] + bn);
        }
    }
}

// ---------------------------------------------------------------------------
// Recurrence: 256 blocks = 4 (q) x 64 (b); bid = q*64 + b so partner blocks
// are congruent mod 8 (same XCD under round-robin). 320 threads: t = g*64+r
// owns weight row n = g*256 + q*64 + r in 128 VGPRs.
// Per step: reg-matvec -> local gates for j in [64q,64q+64) -> publish h/c f16
// (parity buffer) + release tag -> acquire partner tags -> stage h/c to LDS.
// ---------------------------------------------------------------------------
__global__ __launch_bounds__(320) void recur(const float* __restrict__ tsp,
        const f16* __restrict__ Wpk, const f16* __restrict__ Xbuf,
        const float* __restrict__ Wdb, const float* __restrict__ bdv,
        f16* __restrict__ hx, f16* __restrict__ cx,
        unsigned int* __restrict__ tags, float* __restrict__ out) {
    __shared__ __align__(16) f16 hv_f16[512];   // [0..255]=h, [256..511]=c
    __shared__ float pre_s[320];

    const int tid = threadIdx.x;
    const int bid = blockIdx.x;
    const int q = bid >> 6;          // 0..3   (weight-row quarter)
    const int b = bid & 63;          // batch
    const int g = tid >> 6;          // matrix 0..4 (i,f,o,c,d)
    const int r = tid & 63;
    const int n = g * 256 + q * 64 + r;   // global weight row

    // ---- load this thread's weight row into registers (once) ----
    f16x2 w[128];
    {
        const uint4* wsrc = reinterpret_cast<const uint4*>(Wpk + (size_t)n * 256);
        #pragma unroll
        for (int i = 0; i < 32; ++i) {
            uint4 v = wsrc[i];
            w[4 * i + 0] = __builtin_bit_cast(f16x2, v.x);
            w[4 * i + 1] = __builtin_bit_cast(f16x2, v.y);
            w[4 * i + 2] = __builtin_bit_cast(f16x2, v.z);
            w[4 * i + 3] = __builtin_bit_cast(f16x2, v.w);
        }
    }

    // ---- init state ----
    if (tid < 256) { hv_f16[tid] = (f16)0; hv_f16[256 + tid] = (f16)0; }
    const int j = q * 64 + r;        // hidden index this thread owns (if tid<64)
    float cj = 0.0f, bD = 0.0f;
    if (tid < 64) bD = Wdb[j] + bdv[j];
    __syncthreads();

    const int voff = (g == 4) ? 256 : 0;     // d-rows consume c, others h
    unsigned int* tg = tags + (size_t)b * 64;  // [parity][32] padded lines
    f16* hxb = hx + (size_t)b * 512;           // [parity][256]
    f16* cxb = cx + (size_t)b * 512;

    for (int s = 0; s < 512; ++s) {
        // prefetch x-projections + timestamp (used after the matvec barrier)
        float xi = 0.f, xf = 0.f, xo = 0.f, xc = 0.f, ts = 0.f;
        const size_t m = (size_t)b * 512 + s;
        if (tid < 64) {
            const f16* xp = Xbuf + m * 1024 + j;
            xi = (float)xp[0];   xf = (float)xp[256];
            xo = (float)xp[512]; xc = (float)xp[768];
            ts = tsp[m];
        }

        // ---- matvec from registers against LDS-broadcast h/c ----
        float a0 = 0.f, a1 = 0.f, a2 = 0.f, a3 = 0.f;
        #pragma unroll
        for (int ii = 0; ii < 32; ++ii) {
            f16x8 hv = *reinterpret_cast<const f16x8*>(&hv_f16[voff + ii * 8]);
            a0 = fdot2f(w[4 * ii + 0], __builtin_shufflevector(hv, hv, 0, 1), a0);
            a1 = fdot2f(w[4 * ii + 1], __builtin_shufflevector(hv, hv, 2, 3), a1);
            a2 = fdot2f(w[4 * ii + 2], __builtin_shufflevector(hv, hv, 4, 5), a2);
            a3 = fdot2f(w[4 * ii + 3], __builtin_shufflevector(hv, hv, 6, 7), a3);
        }
        pre_s[tid] = (a0 + a1) + (a2 + a3);
        __syncthreads();

        const int p = s & 1;
        if (tid < 64) {
            float T    = 1.0f / __logf(ts + 2.7183f);
            float CST  = tanh_fast(pre_s[256 + tid] + bD);
            float cdec = cj + (T - 1.0f) * CST;
            float ig = sigm(xi + pre_s[tid]);
            float fg = sigm(xf + pre_s[64 + tid]);
            float og = sigm(xo + pre_s[128 + tid]);
            float Cn = tanh_fast(xc + pre_s[192 + tid]);
            cj = fg * cdec + ig * Cn;
            float hn = og * tanh_fast(cj);
            const size_t oi = m * 256 + j;
            out[oi]            = hn;
            out[BSH_ + oi]     = hn;
            out[2 * BSH_ + oi] = cj;
            if (s != 511) {
                hxb[p * 256 + j] = (f16)hn;
                cxb[p * 256 + j] = (f16)cj;
            }
        }
        if (s == 511) break;

        __syncthreads();   // drains each wave's stores (vmcnt) before publish
        if (tid == 0)
            __hip_atomic_store(tg + p * 32 + q, (unsigned)(s + 1),
                               __ATOMIC_RELEASE, __HIP_MEMORY_SCOPE_AGENT);
        if (tid < 4) {
            while (__hip_atomic_load(tg + p * 32 + tid,
                                     __ATOMIC_ACQUIRE, __HIP_MEMORY_SCOPE_AGENT)
                   < (unsigned)(s + 1))
                __builtin_amdgcn_s_sleep(1);
        }
        __syncthreads();

        // ---- stage exchanged h/c into LDS (f16) ----
        if (tid < 64) {
            uint2 v = *reinterpret_cast<const uint2*>(hxb + p * 256 + tid * 4);
            *reinterpret_cast<uint2*>(&hv_f16[tid * 4]) = v;
        } else if (tid < 128) {
            const int u = tid - 64;
            uint2 v = *reinterpret_cast<const uint2*>(cxb + p * 256 + u * 4);
            *reinterpret_cast<uint2*>(&hv_f16[256 + u * 4]) = v;
        }
        __syncthreads();
    }
}

// ---------------------------------------------------------------------------
extern "C" void kernel_launch(void* const* d_in, const int* in_sizes, int n_in,
                              void* d_out, int out_size, void* d_ws, size_t ws_size,
                              hipStream_t stream) {
    const float* inputs = (const float*)d_in[0];
    const float* tsp    = (const float*)d_in[1];
    const float* Wi_w = (const float*)d_in[2],  * Wi_b = (const float*)d_in[3];
    const float* Ui_w = (const float*)d_in[4],  * Ui_b = (const float*)d_in[5];
    const float* Wf_w = (const float*)d_in[6],  * Wf_b = (const float*)d_in[7];
    const float* Uf_w = (const float*)d_in[8],  * Uf_b = (const float*)d_in[9];
    const float* Wo_w = (const float*)d_in[10], * Wo_b = (const float*)d_in[11];
    const float* Uo_w = (const float*)d_in[12], * Uo_b = (const float*)d_in[13];
    const float* Wc_w = (const float*)d_in[14], * Wc_b = (const float*)d_in[15];
    const float* Uc_w = (const float*)d_in[16], * Uc_b = (const float*)d_in[17];
    const float* Wd_w = (const float*)d_in[18], * Wd_b = (const float*)d_in[19];
    const float* bi = (const float*)d_in[20], * bf_ = (const float*)d_in[21];
    const float* bo = (const float*)d_in[22], * bc  = (const float*)d_in[23];
    const float* bd = (const float*)d_in[24];

    // workspace layout (16B-aligned):
    //   Xbuf  f16  [32768][1024]   67,108,864 B @ 0
    //   W4    bf16 [1024][256]        524,288 B @ 67,108,864
    //   bias4 f32  [1024]               4,096 B @ 67,633,152
    //   Wpk   f16  [1280][256]        655,360 B @ 67,637,248
    //   hx    f16  [64][2][256]        65,536 B @ 68,292,608
    //   cx    f16  [64][2][256]        65,536 B @ 68,358,144
    //   tags  u32  [64][2][32]         16,384 B @ 68,423,680   (128B/line pad)
    char* ws = (char*)d_ws;
    f16*            Xbuf  = (f16*)ws;
    unsigned short* W4    = (unsigned short*)(ws + 67108864);
    float*          bias4 = (float*)(ws + 67633152);
    f16*            Wpk   = (f16*)(ws + 67637248);
    f16*            hx    = (f16*)(ws + 68292608);
    f16*            cx    = (f16*)(ws + 68358144);
    unsigned int*   tags  = (unsigned int*)(ws + 68423680);

    prep_w4<<<1024, 256, 0, stream>>>(Wi_w, Wf_w, Wo_w, Wc_w,
                                      Wi_b, Wf_b, Wo_b, Wc_b,
                                      Ui_b, Uf_b, Uo_b, Uc_b,
                                      bi, bf_, bo, bc, W4, bias4);
    prep_wrow<<<1280, 256, 0, stream>>>(Ui_w, Uf_w, Uo_w, Uc_w, Wd_w, Wpk);
    prep_zero<<<16, 256, 0, stream>>>(tags);
    proj_gemm<<<8192, 256, 0, stream>>>(inputs, W4, bias4, Xbuf);
    recur<<<256, 320, 0, stream>>>(tsp, Wpk, Xbuf, Wd_b, bd, hx, cx, tags, (float*)d_out);
}